// Round 5
// baseline (955.526 us; speedup 1.0000x reference)
//
#include <hip/hip_runtime.h>
#include <stdint.h>

#define N_NODES 100000
#define N_EDGES 3200000
#define DIM 128
#define NPAD 100032    // 1563 * 64
#define NPAD8 (NPAD * 8)   // uint32s per column-slice (32B per node)
#define NBINS 391      // ceil(100000 / 256) -- 256 nodes per bin
#define BCAP 10240     // bin capacity; mean 8192
#define EPB 4096       // edges per bin_kernel block (16/thread)
#define NCHUNK 3126    // NPAD / 32 nodes per gather chunk

typedef short short8 __attribute__((ext_vector_type(8)));
typedef float f32x4 __attribute__((ext_vector_type(4)));

__device__ __forceinline__ short f2bf(float x) {
    uint32_t u = __builtin_bit_cast(uint32_t, x);
    u += 0x7fffu + ((u >> 16) & 1u);   // round-to-nearest-even
    return (short)(u >> 16);
}
__device__ __forceinline__ float bflo(uint32_t p) {
    return __builtin_bit_cast(float, p << 16);
}
__device__ __forceinline__ float bfhi(uint32_t p) {
    return __builtin_bit_cast(float, p & 0xffff0000u);
}
__device__ __forceinline__ uint32_t pack2(float x, float y) {
    return (uint32_t)(uint16_t)f2bf(x) | ((uint32_t)(uint16_t)f2bf(y) << 16);
}

// ---- K1: fused prep: feat->bf16 sharded cast, W transpose, counters -----
// featsh layout: slice p in [0,8): featsh[p*NPAD8 + node*8 + c], c in [0,8)
// (slice p holds bf16 columns [16p, 16p+16) of each row, 32 B per node)
__global__ __launch_bounds__(256) void prep_kernel(const float* __restrict__ feat,
                                                   uint32_t* __restrict__ featsh,
                                                   const float* __restrict__ w1,
                                                   const float* __restrict__ w2,
                                                   short* __restrict__ w1t,
                                                   short* __restrict__ w2t,
                                                   int* __restrict__ bincnt,
                                                   int* __restrict__ qcur) {
    int b = blockIdx.x, t = threadIdx.x;
    if (b < 12500) {                       // cast: 3.2M float4s
        int i = b * 256 + t;
        float4 f = ((const float4*)feat)[i];
        int n = i >> 5;                    // node (32 float4 per row)
        int fq = i & 31;                   // float4 index within row
        int p = fq >> 2;                   // slice
        int o = (fq & 3) * 2;              // uint32 offset within slice
        featsh[p * NPAD8 + n * 8 + o]     = pack2(f.x, f.y);
        featsh[p * NPAD8 + n * 8 + o + 1] = pack2(f.z, f.w);
    } else if (b < 12564) {                // weight transpose: 16384 elems
        int i = (b - 12500) * 256 + t;
        int k = i >> 7, n = i & 127;
        w1t[n * DIM + k] = f2bf(w1[i]);
        w2t[n * DIM + k] = f2bf(w2[i]);
    } else if (b < 12566) {                // zero bincnt (512 ints)
        bincnt[(b - 12564) * 256 + t] = 0;
    } else {                               // zero the 8 shard queues
        if (t < 8) qcur[t] = 0;
    }
}

// ---- K3a: bin edges by dst>>8, LDS counting-sort, coalesced write-out ---
__global__ __launch_bounds__(256) void bin_kernel(const int* __restrict__ src,
                                                  const int* __restrict__ dst,
                                                  int* __restrict__ bincnt,
                                                  uint32_t* __restrict__ binpair) {
    __shared__ int hist[512];
    __shared__ int scanv[512];
    __shared__ int scan256[256];
    __shared__ int gbase[NBINS];
    __shared__ int cursor[NBINS];
    __shared__ uint32_t sorted[EPB];
    __shared__ int saddr[EPB];
    int t = threadIdx.x;
    for (int i = t; i < 512; i += 256) hist[i] = 0;
    __syncthreads();
    int e0 = blockIdx.x * EPB;
    int nn = min(EPB, N_EDGES - e0);
    int d[16];
#pragma unroll
    for (int i = 0; i < 16; i++) {
        int idx = i * 256 + t;
        d[i] = (idx < nn) ? dst[e0 + idx] : -1;
        if (d[i] >= 0) atomicAdd(&hist[d[i] >> 8], 1);
    }
    __syncthreads();
    int h0 = hist[2 * t], h1 = hist[2 * t + 1];
    scan256[t] = h0 + h1;
    __syncthreads();
    for (int dd = 1; dd < 256; dd <<= 1) {
        int v = (t >= dd) ? scan256[t - dd] : 0;
        __syncthreads();
        scan256[t] += v;
        __syncthreads();
    }
    int pairExcl = scan256[t] - (h0 + h1);
    scanv[2 * t] = pairExcl;
    scanv[2 * t + 1] = pairExcl + h0;
    for (int b = t; b < NBINS; b += 256) {
        int h = hist[b];
        gbase[b] = h ? atomicAdd(&bincnt[b], h) : 0;
        cursor[b] = 0;
    }
    __syncthreads();
#pragma unroll
    for (int i = 0; i < 16; i++) {
        if (d[i] >= 0) {
            int b = d[i] >> 8;
            int slot = atomicAdd(&cursor[b], 1);
            int p = scanv[b] + slot;
            int g = gbase[b] + slot;
            int e = e0 + i * 256 + t;
            sorted[p] = (uint32_t)src[e] | ((uint32_t)(d[i] & 255) << 24);
            saddr[p] = (g < BCAP) ? (b * BCAP + g) : -1;
        }
    }
    __syncthreads();
    for (int i = t; i < nn; i += 256) {
        int a = saddr[i];
        if (a >= 0) binpair[a] = sorted[i];
    }
}

// ---- K3b: per-bin counting sort -> CSR ----------------------------------
__global__ __launch_bounds__(256) void csr_kernel(const int* __restrict__ bincnt,
                                                  const uint32_t* __restrict__ binpair,
                                                  int* __restrict__ rowptr,
                                                  int* __restrict__ csr) {
    __shared__ int hist[256];
    __shared__ int cursor[256];
    __shared__ int sc[256];
    __shared__ int binbase_s;
    int b = blockIdx.x;
    int t = threadIdx.x;
    int partial = 0;
    for (int j = t; j < b; j += 256) partial += min(bincnt[j], BCAP);
    sc[t] = partial;
    __syncthreads();
    for (int dd = 128; dd > 0; dd >>= 1) {
        if (t < dd) sc[t] += sc[t + dd];
        __syncthreads();
    }
    if (t == 0) binbase_s = sc[0];
    hist[t] = 0;
    __syncthreads();
    int binbase = binbase_s;
    int cntb = min(bincnt[b], BCAP);
    const uint32_t* pairs = binpair + (size_t)b * BCAP;
    for (int i = t; i < cntb; i += 256)
        atomicAdd(&hist[pairs[i] >> 24], 1);
    __syncthreads();
    int val = hist[t];
    sc[t] = val;
    __syncthreads();
    for (int dd = 1; dd < 256; dd <<= 1) {
        int addv = (t >= dd) ? sc[t - dd] : 0;
        __syncthreads();
        sc[t] += addv;
        __syncthreads();
    }
    int excl = sc[t] - val;
    rowptr[(b << 8) + t] = binbase + excl;
    cursor[t] = excl;
    __syncthreads();
    for (int i = t; i < cntb; i += 256) {
        uint32_t p = pairs[i];
        int s2 = atomicAdd(&cursor[p >> 24], 1);
        csr[binbase + s2] = (int)(p & 0x00FFFFFFu);
    }
}

// ---- K4: XCD-sharded gather. XCD x owns column-slice x (3.2 MB, fits its
// 4 MB L2). Work-queue per slice; fallback scan of other queues guarantees
// correctness under ANY block->XCD mapping. 8 lanes per node, lane owns 2
// bf16 columns -> no cross-lane reduction; output stores fully coalesced.
__global__ __launch_bounds__(256) void gather_kernel(const uint32_t* __restrict__ featsh,
                                                     const int* __restrict__ rowptr,
                                                     const int* __restrict__ csr,
                                                     const float* __restrict__ eps,
                                                     uint32_t* __restrict__ hbfsh,
                                                     int* __restrict__ qcur) {
    __shared__ int chunk_s;
    int xcc;
    asm volatile("s_getreg_b32 %0, hwreg(HW_REG_XCC_ID)" : "=s"(xcc));
    xcc &= 7;
    int t = threadIdx.x;
    int g = t >> 3;           // node-group within chunk [0,32)
    int c = t & 7;            // uint32 column within slice [0,8)
    float e1 = 1.0f + eps[0];
    for (int qo = 0; qo < 8; qo++) {
        int q = (xcc + qo) & 7;                 // own queue first, then steal
        const uint32_t* tab  = featsh + (size_t)q * NPAD8;
        uint32_t*       otab = hbfsh  + (size_t)q * NPAD8;
        for (;;) {
            if (t == 0) chunk_s = atomicAdd(&qcur[q], 1);
            __syncthreads();
            int chunk = chunk_s;
            __syncthreads();
            if (chunk >= NCHUNK) break;
            int v = chunk * 32 + g;
            if (v >= N_NODES) {
                otab[v * 8 + c] = 0;            // pad rows -> zero
            } else {
                uint32_t sf = tab[v * 8 + c];   // self row slice (L2-hit)
                float a0 = e1 * bflo(sf);
                float a1 = e1 * bfhi(sf);
                int s = rowptr[v], e = rowptr[v + 1];
                for (int j = s; j < e; j += 8) {
                    int mm = e - 1;
                    int u0 = csr[min(j,     mm)], u1 = csr[min(j + 1, mm)];
                    int u2 = csr[min(j + 2, mm)], u3 = csr[min(j + 3, mm)];
                    int u4 = csr[min(j + 4, mm)], u5 = csr[min(j + 5, mm)];
                    int u6 = csr[min(j + 6, mm)], u7 = csr[min(j + 7, mm)];
                    uint32_t q0 = tab[u0 * 8 + c], q1 = tab[u1 * 8 + c];
                    uint32_t q2 = tab[u2 * 8 + c], q3 = tab[u3 * 8 + c];
                    uint32_t q4 = tab[u4 * 8 + c], q5 = tab[u5 * 8 + c];
                    uint32_t q6 = tab[u6 * 8 + c], q7 = tab[u7 * 8 + c];
                    a0 += bflo(q0); a1 += bfhi(q0);
                    if (j + 1 < e) { a0 += bflo(q1); a1 += bfhi(q1); }
                    if (j + 2 < e) { a0 += bflo(q2); a1 += bfhi(q2); }
                    if (j + 3 < e) { a0 += bflo(q3); a1 += bfhi(q3); }
                    if (j + 4 < e) { a0 += bflo(q4); a1 += bfhi(q4); }
                    if (j + 5 < e) { a0 += bflo(q5); a1 += bfhi(q5); }
                    if (j + 6 < e) { a0 += bflo(q6); a1 += bfhi(q6); }
                    if (j + 7 < e) { a0 += bflo(q7); a1 += bfhi(q7); }
                }
                otab[v * 8 + c] = pack2(a0, a1);
            }
        }
    }
}

// ---- K5: fused 2-layer MLP via bf16 MFMA 16x16x32 (slice-major h input) -
__global__ __launch_bounds__(256) void mlp_kernel(const uint32_t* __restrict__ hbfsh,
                                                  const short* __restrict__ w1t,
                                                  const short* __restrict__ w2t,
                                                  const float* __restrict__ b1,
                                                  const float* __restrict__ b2,
                                                  float* __restrict__ out) {
    __shared__ __align__(16) short h1s[4][16 * 136];
    const int wave = threadIdx.x >> 6;
    const int lane = threadIdx.x & 63;
    const int l15 = lane & 15;
    const int quad = lane >> 4;

    float b1v[8], b2v[8];
#pragma unroll
    for (int n = 0; n < 8; n++) {
        b1v[n] = b1[n * 16 + l15];
        b2v[n] = b2[n * 16 + l15];
    }

    const int ntiles = NPAD / 64;
    for (int tile = blockIdx.x; tile < ntiles; tile += gridDim.x) {
        int row0 = tile * 64 + wave * 16;
        f32x4 acc[8];
#pragma unroll
        for (int n = 0; n < 8; n++) acc[n] = (f32x4){0.f, 0.f, 0.f, 0.f};
#pragma unroll
        for (int kb = 0; kb < DIM; kb += 32) {
            int col0 = kb + quad * 8;          // A-frag k-offset
            int p = col0 >> 4;                 // slice
            int half = (col0 >> 3) & 1;        // 16B half within slice
            short8 a = *(const short8*)&hbfsh[(size_t)p * NPAD8 +
                                              (row0 + l15) * 8 + half * 4];
#pragma unroll
            for (int n = 0; n < 8; n++) {
                short8 b = *(const short8*)&w1t[(n * 16 + l15) * DIM + kb + quad * 8];
                acc[n] = __builtin_amdgcn_mfma_f32_16x16x32_bf16(a, b, acc[n], 0, 0, 0);
            }
        }
#pragma unroll
        for (int n = 0; n < 8; n++) {
#pragma unroll
            for (int r = 0; r < 4; r++) {
                float v = acc[n][r] + b1v[n];
                v = v > 0.f ? v : 0.f;
                h1s[wave][(quad * 4 + r) * 136 + n * 16 + l15] = f2bf(v);
            }
        }
        __syncthreads();
        f32x4 acc2[8];
#pragma unroll
        for (int n = 0; n < 8; n++) acc2[n] = (f32x4){0.f, 0.f, 0.f, 0.f};
#pragma unroll
        for (int kb = 0; kb < DIM; kb += 32) {
            short8 a2 = *(const short8*)&h1s[wave][l15 * 136 + kb + quad * 8];
#pragma unroll
            for (int n = 0; n < 8; n++) {
                short8 b = *(const short8*)&w2t[(n * 16 + l15) * DIM + kb + quad * 8];
                acc2[n] = __builtin_amdgcn_mfma_f32_16x16x32_bf16(a2, b, acc2[n], 0, 0, 0);
            }
        }
#pragma unroll
        for (int n = 0; n < 8; n++) {
#pragma unroll
            for (int r = 0; r < 4; r++) {
                int row = row0 + quad * 4 + r;
                if (row < N_NODES)
                    out[row * DIM + n * 16 + l15] = acc2[n][r] + b2v[n];
            }
        }
        __syncthreads();
    }
}

extern "C" void kernel_launch(void* const* d_in, const int* in_sizes, int n_in,
                              void* d_out, int out_size, void* d_ws, size_t ws_size,
                              hipStream_t stream) {
    const float* feat = (const float*)d_in[0];
    const int* src    = (const int*)d_in[1];
    const int* dst    = (const int*)d_in[2];
    const float* eps  = (const float*)d_in[3];
    const float* W1   = (const float*)d_in[4];
    const float* b1   = (const float*)d_in[5];
    const float* W2   = (const float*)d_in[6];
    const float* b2   = (const float*)d_in[7];
    float* out = (float*)d_out;

    char* ws = (char*)d_ws;
    int*      bincnt  = (int*)ws;                          //         2,048 B
    int*      qcur    = (int*)(ws + 2048);                 //            64 B
    int*      rowptr  = (int*)(ws + 2112);                 //       401,408 B
    int*      csr     = (int*)(ws + 403520);               //    12,800,000 B
    uint32_t* binpair = (uint32_t*)(ws + 13203520);        //    16,015,360 B
    uint32_t* featsh  = (uint32_t*)(ws + 29218880);        //    25,608,192 B
    uint32_t* hbfsh   = (uint32_t*)(ws + 54827072);        //    25,608,192 B
    short*    w1t     = (short*)(ws + 80435264);           //        32,768 B
    short*    w2t     = (short*)(ws + 80468032);           // ends 80,500,800 B

    prep_kernel<<<12567, 256, 0, stream>>>(feat, featsh, W1, W2, w1t, w2t,
                                           bincnt, qcur);
    bin_kernel<<<(N_EDGES + EPB - 1) / EPB, 256, 0, stream>>>(src, dst, bincnt, binpair);
    csr_kernel<<<NBINS, 256, 0, stream>>>(bincnt, binpair, rowptr, csr);
    gather_kernel<<<4096, 256, 0, stream>>>(featsh, rowptr, csr, eps, hbfsh, qcur);
    mlp_kernel<<<1563, 256, 0, stream>>>(hbfsh, w1t, w2t, b1, b2, out);
}